// Round 5
// baseline (551.092 us; speedup 1.0000x reference)
//
#include <hip/hip_runtime.h>
#include <cstdint>
#include <cstddef>

// Problem dims (fixed)
#define TOK   1024   // B*T
#define DIMX  512
#define HID   2048
#define DM    256
#define GENH  512
#define RR    64
#define O3BASE 65536 // start row of path-3 block in gen_w2 (2*R*DIM)

typedef __bf16 bf16x8 __attribute__((ext_vector_type(8)));
typedef float  f32x4  __attribute__((ext_vector_type(4)));

__device__ __forceinline__ unsigned short f2bf(float f) {
  union { float f; uint32_t u; } v; v.f = f;
  return (unsigned short)((v.u + 0x7fffu + ((v.u >> 16) & 1u)) >> 16);
}
__device__ __forceinline__ float bf2f(unsigned short h) {
  union { uint32_t u; float f; } v; v.u = (uint32_t)h << 16;
  return v.f;
}
__device__ __forceinline__ float silu_f(float x) { return x / (1.f + __expf(-x)); }

__device__ __forceinline__ void async_copy16(const void* g, void* l) {
  __builtin_amdgcn_global_load_lds(
      (const __attribute__((address_space(1))) void*)g,
      (__attribute__((address_space(3))) void*)l, 16, 0, 0);
}

__device__ __forceinline__ void cast8(const float* __restrict__ src,
                                      unsigned short* __restrict__ dst, size_t i) {
  float4 v0 = *(const float4*)(src + i);
  float4 v1 = *(const float4*)(src + i + 4);
  ushort4 h0, h1;
  h0.x = f2bf(v0.x); h0.y = f2bf(v0.y); h0.z = f2bf(v0.z); h0.w = f2bf(v0.w);
  h1.x = f2bf(v1.x); h1.y = f2bf(v1.y); h1.z = f2bf(v1.z); h1.w = f2bf(v1.w);
  *(ushort4*)(dst + i)     = h0;
  *(ushort4*)(dst + i + 4) = h1;
}

// ---------------------------------------------------------------------------
// f32 -> bf16 cast (for gen_w2)
// ---------------------------------------------------------------------------
__global__ __launch_bounds__(256) void cast_bf16_kernel(
    const float* __restrict__ src, unsigned short* __restrict__ dst) {
  cast8(src, dst, ((size_t)blockIdx.x * 256 + threadIdx.x) * 8);
}

// ---------------------------------------------------------------------------
// Stage one [ROWS x 64] bf16 tile into LDS via global_load_lds width=16,
// fetch-side XOR swizzle (chunk' = chunk ^ (row&7)) -> conflict-free b128.
// ---------------------------------------------------------------------------
template<int ROWS>
__device__ __forceinline__ void stage_tile(
    const unsigned short* __restrict__ base, size_t row0, int stride, int kofs,
    unsigned short* Ls, int tid) {
  constexpr int IT = ROWS / 32;           // 16B chunks per thread
  const int wave = tid >> 6, lane = tid & 63;
#pragma unroll
  for (int j = 0; j < IT; ++j) {
    int s   = wave * (IT * 64) + j * 64 + lane;   // linear 16B slot
    int row = s >> 3;
    int kc  = (s & 7) ^ (row & 7);                // fetch-side swizzle
    const unsigned short* g = base + (row0 + (size_t)row) * (size_t)stride + kofs + kc * 8;
    async_copy16(g, (char*)Ls + wave * (IT * 1024) + j * 1024);
  }
}

// ---------------------------------------------------------------------------
// Core: C[128 x 128] = A[128 x K] @ B[128 x K]^T (both bf16, K-contig) via
// mfma_f32_16x16x32_bf16, 4 waves 2x2. Ends with __syncthreads().
// ---------------------------------------------------------------------------
template<int KLEN>
__device__ __forceinline__ void mfma_tile_nt(
    const unsigned short* __restrict__ Abf, size_t a_row0, int astride,
    const unsigned short* __restrict__ Bbf, size_t b_row0, int bstride, int k0,
    unsigned short* As, unsigned short* Bs, f32x4 (&acc)[4][4]) {
  const int tid  = threadIdx.x;
  const int lane = tid & 63;
  const int wave = tid >> 6;
  const int m0 = (wave >> 1) * 64, n0 = (wave & 1) * 64;

  for (int kk = 0; kk < KLEN; kk += 64) {
    stage_tile<128>(Abf, a_row0, astride, k0 + kk, As, tid);
    stage_tile<128>(Bbf, b_row0, bstride, k0 + kk, Bs, tid);
    __syncthreads();
#pragma unroll
    for (int ks = 0; ks < 2; ++ks) {
      int cbase = ks * 4 + (lane >> 4);
      int koff  = (cbase ^ (lane & 7)) * 8;   // row&7 == lane&7 for all frags
      bf16x8 a[4], b[4];
#pragma unroll
      for (int mf = 0; mf < 4; ++mf)
        a[mf] = *(const bf16x8*)(As + (m0 + mf * 16 + (lane & 15)) * 64 + koff);
#pragma unroll
      for (int nf = 0; nf < 4; ++nf)
        b[nf] = *(const bf16x8*)(Bs + (n0 + nf * 16 + (lane & 15)) * 64 + koff);
#pragma unroll
      for (int mf = 0; mf < 4; ++mf)
#pragma unroll
        for (int nf = 0; nf < 4; ++nf)
          acc[mf][nf] = __builtin_amdgcn_mfma_f32_16x16x32_bf16(
              a[mf], b[nf], acc[mf][nf], 0, 0, 0);
    }
    __syncthreads();
  }
}

__device__ __forceinline__ void zero_acc4(f32x4 (&acc)[4][4]) {
#pragma unroll
  for (int i = 0; i < 4; ++i)
#pragma unroll
    for (int j = 0; j < 4; ++j) {
      f32x4 z = {0.f, 0.f, 0.f, 0.f};
      acc[i][j] = z;
    }
}

// ---------------------------------------------------------------------------
// prep: hg = silu(m_tok @ gen_w1^T + gen_b1) -> bf16; x -> bf16;
// also casts W1/W2/W3 to bf16 (folded to save launches).
// ---------------------------------------------------------------------------
__global__ __launch_bounds__(256) void prep_kernel(
    const float* __restrict__ x, const float* __restrict__ m_tok,
    const float* __restrict__ gen_w1, const float* __restrict__ gen_b1,
    const float* __restrict__ W1, const float* __restrict__ W2,
    const float* __restrict__ W3,
    unsigned short* __restrict__ xb, unsigned short* __restrict__ hgb,
    unsigned short* __restrict__ W1b, unsigned short* __restrict__ W2b,
    unsigned short* __restrict__ W3b) {
  __shared__ float mt[4 * DM];
  const int tid = threadIdx.x;
  const size_t t0 = (size_t)blockIdx.x * 4;
#pragma unroll
  for (int k = 0; k < 4; ++k) mt[k * 256 + tid] = m_tok[t0 * DM + k * 256 + tid];
#pragma unroll
  for (int k = 0; k < 8; ++k) {
    size_t idx = t0 * DIMX + k * 256 + tid;
    xb[idx] = f2bf(x[idx]);
  }
  // folded weight casts: 1,048,576 elems each = 2 chunks/thread each
  {
    size_t base = ((size_t)blockIdx.x * 256 + tid) * 8;
#pragma unroll
    for (int it = 0; it < 2; ++it) {
      size_t idx = base + (size_t)it * 524288;
      cast8(W1, W1b, idx);
      cast8(W2, W2b, idx);
      cast8(W3, W3b, idx);
    }
  }
  __syncthreads();
#pragma unroll
  for (int hh = 0; hh < 2; ++hh) {
    int h = hh * 256 + tid;
    float a0, a1, a2, a3;
    a0 = a1 = a2 = a3 = gen_b1[h];
    const float* wr = gen_w1 + (size_t)h * DM;
    for (int d = 0; d < DM; d += 4) {
      float4 w = *(const float4*)(wr + d);
      a0 += w.x * mt[d]       + w.y * mt[d + 1]       + w.z * mt[d + 2]       + w.w * mt[d + 3];
      a1 += w.x * mt[256 + d] + w.y * mt[256 + d + 1] + w.z * mt[256 + d + 2] + w.w * mt[256 + d + 3];
      a2 += w.x * mt[512 + d] + w.y * mt[512 + d + 1] + w.z * mt[512 + d + 2] + w.w * mt[512 + d + 3];
      a3 += w.x * mt[768 + d] + w.y * mt[768 + d + 1] + w.z * mt[768 + d + 2] + w.w * mt[768 + d + 3];
    }
    hgb[(t0 + 0) * GENH + h] = f2bf(silu_f(a0));
    hgb[(t0 + 1) * GENH + h] = f2bf(silu_f(a1));
    hgb[(t0 + 2) * GENH + h] = f2bf(silu_f(a2));
    hgb[(t0 + 3) * GENH + h] = f2bf(silu_f(a3));
  }
}

// ---------------------------------------------------------------------------
// ffn12: fused x@W1^T / x@W2^T + bias + silu-mul -> hb (bf16).
// Tile 64 tok x 128 o, grid 256 blocks. Waves 2x2 (32x64 each).
// ---------------------------------------------------------------------------
__global__ __launch_bounds__(256) void ffn12_kernel(
    const unsigned short* __restrict__ xb, const unsigned short* __restrict__ W1b,
    const unsigned short* __restrict__ W2b, const float* __restrict__ pb1,
    const float* __restrict__ pb2, unsigned short* __restrict__ hb) {
  __shared__ unsigned short As[64 * 64];
  __shared__ unsigned short B1s[128 * 64];
  __shared__ unsigned short B2s[128 * 64];
  const int tid = threadIdx.x, lane = tid & 63, wave = tid >> 6;
  const int ob = blockIdx.x & 15, tb = blockIdx.x >> 4;
  const size_t t0 = (size_t)tb * 64, o0 = (size_t)ob * 128;
  const int m0 = (wave >> 1) * 32, n0 = (wave & 1) * 64;

  f32x4 acc1[2][4], acc2[2][4];
#pragma unroll
  for (int i = 0; i < 2; ++i)
#pragma unroll
    for (int j = 0; j < 4; ++j) {
      f32x4 z = {0.f, 0.f, 0.f, 0.f};
      acc1[i][j] = z; acc2[i][j] = z;
    }

  for (int kk = 0; kk < DIMX; kk += 64) {
    stage_tile<64>(xb, t0, DIMX, kk, As, tid);
    stage_tile<128>(W1b, o0, DIMX, kk, B1s, tid);
    stage_tile<128>(W2b, o0, DIMX, kk, B2s, tid);
    __syncthreads();
#pragma unroll
    for (int ks = 0; ks < 2; ++ks) {
      int cbase = ks * 4 + (lane >> 4);
      int koff  = (cbase ^ (lane & 7)) * 8;
      bf16x8 a[2], b1[4], b2[4];
#pragma unroll
      for (int mf = 0; mf < 2; ++mf)
        a[mf] = *(const bf16x8*)(As + (m0 + mf * 16 + (lane & 15)) * 64 + koff);
#pragma unroll
      for (int nf = 0; nf < 4; ++nf) {
        b1[nf] = *(const bf16x8*)(B1s + (n0 + nf * 16 + (lane & 15)) * 64 + koff);
        b2[nf] = *(const bf16x8*)(B2s + (n0 + nf * 16 + (lane & 15)) * 64 + koff);
      }
#pragma unroll
      for (int mf = 0; mf < 2; ++mf)
#pragma unroll
        for (int nf = 0; nf < 4; ++nf) {
          acc1[mf][nf] = __builtin_amdgcn_mfma_f32_16x16x32_bf16(a[mf], b1[nf], acc1[mf][nf], 0, 0, 0);
          acc2[mf][nf] = __builtin_amdgcn_mfma_f32_16x16x32_bf16(a[mf], b2[nf], acc2[mf][nf], 0, 0, 0);
        }
    }
    __syncthreads();
  }

  const int q = lane >> 4;
  float b1v[4], b2v[4];
#pragma unroll
  for (int nf = 0; nf < 4; ++nf) {
    b1v[nf] = pb1[o0 + n0 + nf * 16 + (lane & 15)];
    b2v[nf] = pb2[o0 + n0 + nf * 16 + (lane & 15)];
  }
#pragma unroll
  for (int mf = 0; mf < 2; ++mf)
#pragma unroll
    for (int nf = 0; nf < 4; ++nf)
#pragma unroll
      for (int rg = 0; rg < 4; ++rg) {
        size_t trow = t0 + m0 + mf * 16 + q * 4 + rg;
        size_t col  = o0 + n0 + nf * 16 + (lane & 15);
        float v1 = acc1[mf][nf][rg] + b1v[nf];
        float v2 = acc2[mf][nf][rg] + b2v[nf];
        hb[trow * HID + col] = f2bf(silu_f(v1) * v2);
      }
}

// ---------------------------------------------------------------------------
// gemm3p: yp[slice] = hb @ W3b^T (partial K), plain stores, no bias.
// grid (32, 8): 8 t-tiles x 4 o-tiles x 8 K-slices (KTILE=256) -> 256 blocks.
// ---------------------------------------------------------------------------
__global__ __launch_bounds__(256) void gemm3p_kernel(
    const unsigned short* __restrict__ hb, const unsigned short* __restrict__ W3b,
    float* __restrict__ yp) {
  __shared__ unsigned short As[8192];
  __shared__ unsigned short Bs[8192];
  const int ob = blockIdx.x & 3, tb = blockIdx.x >> 2;
  const size_t o0 = (size_t)ob * 128, t0 = (size_t)tb * 128;
  const int k0 = blockIdx.y * 256;
  f32x4 acc[4][4];
  zero_acc4(acc);
  mfma_tile_nt<256>(hb, t0, HID, W3b, o0, HID, k0, As, Bs, acc);

  const int tid = threadIdx.x, lane = tid & 63, wave = tid >> 6;
  const int m0 = (wave >> 1) * 64, n0 = (wave & 1) * 64;
  float* out = yp + (size_t)blockIdx.y * (TOK * DIMX);
#pragma unroll
  for (int nf = 0; nf < 4; ++nf) {
    int n = n0 + nf * 16 + (lane & 15);
#pragma unroll
    for (int mf = 0; mf < 4; ++mf) {
      int mb = m0 + mf * 16 + ((lane >> 4) << 2);
#pragma unroll
      for (int rg = 0; rg < 4; ++rg)
        out[(t0 + mb + rg) * DIMX + o0 + n] = acc[mf][nf][rg];
    }
  }
}

// ---------------------------------------------------------------------------
// yreduce: ybase = b3 + sum of 8 yp slices. float4/thread.
// ---------------------------------------------------------------------------
__global__ __launch_bounds__(256) void yreduce_kernel(
    const float* __restrict__ yp, const float* __restrict__ b3,
    float* __restrict__ ybase) {
  size_t i = ((size_t)blockIdx.x * 256 + threadIdx.x) * 4;
  int d = (int)(i & (DIMX - 1));
  float4 s = *(const float4*)(b3 + d);
#pragma unroll
  for (int p = 0; p < 8; ++p) {
    float4 v = *(const float4*)(yp + (size_t)p * (TOK * DIMX) + i);
    s.x += v.x; s.y += v.y; s.z += v.z; s.w += v.w;
  }
  *(float4*)(ybase + i) = s;
}

// ---------------------------------------------------------------------------
// memuv: fused paths 1&2. Block = [128 tok x 128 o] tile of w; epilogue
// contracts vs x staged in LDS [128x128] bf16 with address swizzle
// (chunk' = chunk ^ (((row>>2)&3)<<1)); leaders store float4 partials to
// up[p][j][t]. Grid mapping ob-INNER: bx%8 == ob%8 pins all 8 token-tile
// sharers of one w2b strip to the SAME XCD (L2 strip reuse).
// LDS exactly 32 KB -> 5 blocks/CU.
// ---------------------------------------------------------------------------
union SmemUV {
  struct { unsigned short As[8192], Bs[8192]; } ab;
  struct { unsigned short Xs[128 * 128]; } ep;
};

__global__ __launch_bounds__(256) void memuv_kernel(
    const unsigned short* __restrict__ hgb, const unsigned short* __restrict__ w2b,
    const float* __restrict__ gen_b2, const unsigned short* __restrict__ xb,
    float* __restrict__ up) {
  __shared__ SmemUV sm;
  const int bx = blockIdx.x;
  const int ob = bx & 511, tb = bx >> 9;    // ob inner -> XCD-pinned strips
  const size_t o0 = (size_t)ob * 128, t0 = (size_t)tb * 128;
  const int j  = ob >> 2;           // u column (0..127)
  const int d0 = (ob & 3) * 128;    // d-range within the r row

  f32x4 acc[4][4];
  zero_acc4(acc);
  mfma_tile_nt<GENH>(hgb, t0, GENH, w2b, o0, GENH, 0, sm.ab.As, sm.ab.Bs, acc);

  const int tid = threadIdx.x, lane = tid & 63, wave = tid >> 6;
  // stage x tile [128 t x 128 d] bf16 with chunk swizzle ^(((row>>2)&3)<<1)
#pragma unroll
  for (int i = 0; i < 8; ++i) {
    int qq = i * 256 + tid;         // 8-short chunks, 2048 total
    int row = qq >> 4, c = qq & 15;
    const unsigned short* src = xb + (t0 + (size_t)row) * DIMX + d0 + c * 8;
    ushort4 v0 = *(const ushort4*)src;
    ushort4 v1 = *(const ushort4*)(src + 4);
    int cs = c ^ (((row >> 2) & 3) << 1);
    unsigned short* dst = sm.ep.Xs + row * 128 + cs * 8;
    *(ushort4*)dst = v0;
    *(ushort4*)(dst + 4) = v1;
  }
  __syncthreads();

  const int m0 = (wave >> 1) * 64, n0 = (wave & 1) * 64;
  const int q = lane >> 4, l15 = lane & 15;
  float gbv[4];
#pragma unroll
  for (int i = 0; i < 4; ++i)
    gbv[i] = gen_b2[o0 + n0 + i * 16 + l15];

  const int p = (ob & 3) * 2 + (wave & 1);
  float* upd = up + (size_t)p * (128 * 1024) + (size_t)j * 1024 + t0;
#pragma unroll
  for (int mf = 0; mf < 4; ++mf) {
    f32x4 vals;
#pragma unroll
    for (int rg = 0; rg < 4; ++rg) {
      int trow = m0 + mf * 16 + q * 4 + rg;
      int swz  = ((trow >> 2) & 3) << 1;
      float val = 0.f;
#pragma unroll
      for (int nf = 0; nf < 4; ++nf) {
        int col = n0 + nf * 16 + l15;
        int idx = trow * 128 + (((col >> 3) ^ swz) << 3) + (col & 7);
        val += (acc[mf][nf][rg] + gbv[nf]) * bf2f(sm.ep.Xs[idx]);
      }
      val += __shfl_xor(val, 1);
      val += __shfl_xor(val, 2);
      val += __shfl_xor(val, 4);
      val += __shfl_xor(val, 8);
      vals[rg] = val;
    }
    if (l15 == 0)
      *(f32x4*)(upd + m0 + mf * 16 + q * 4) = vals;
  }
}

// ---------------------------------------------------------------------------
// hmem: u = sum of 8 partials (coalesced in t); h_mem = silu(u1)*u2, [t][r].
// ---------------------------------------------------------------------------
__global__ __launch_bounds__(256) void hmem_kernel(
    const float* __restrict__ up, float* __restrict__ hm) {
  int i = blockIdx.x * 256 + threadIdx.x;  // 65536
  int t = i & 1023, r = i >> 10;           // r in 0..63
  float u1 = 0.f, u2 = 0.f;
#pragma unroll
  for (int p = 0; p < 8; ++p) {
    u1 += up[(size_t)p * (128 * 1024) + (size_t)r * 1024 + t];
    u2 += up[(size_t)p * (128 * 1024) + (size_t)(64 + r) * 1024 + t];
  }
  hm[(size_t)t * RR + r] = silu_f(u1) * u2;
}

// ---------------------------------------------------------------------------
// memy: fused path 3. Epilogue contracts vs h_mem in LDS [128x64] f32 with
// chunk swizzle; single-writer y = ybase + g*val. ob-inner grid (XCD pin).
// LDS exactly 32 KB.
// ---------------------------------------------------------------------------
union SmemY {
  struct { unsigned short As[8192], Bs[8192]; } ab;
  struct { float Hs[128 * 64]; } ep;
};

__global__ __launch_bounds__(256) void memy_kernel(
    const unsigned short* __restrict__ hgb, const unsigned short* __restrict__ w2b,
    const float* __restrict__ gen_b2, const float* __restrict__ hmem,
    const float* __restrict__ ybase, const float* __restrict__ mem_gate,
    float* __restrict__ y) {
  __shared__ SmemY sm;
  const int bx = blockIdx.x;
  const int ob = bx & 255, tb = bx >> 8;    // ob inner -> XCD-pinned strips
  const size_t brow0 = (size_t)O3BASE + (size_t)ob * 128;
  const size_t t0 = (size_t)tb * 128;

  f32x4 acc[4][4];
  zero_acc4(acc);
  mfma_tile_nt<GENH>(hgb, t0, GENH, w2b, brow0, GENH, 0, sm.ab.As, sm.ab.Bs, acc);

  const int tid = threadIdx.x, lane = tid & 63, wave = tid >> 6;
  // stage h_mem tile [128 t x 64 r] f32, chunk swizzle ^(((row>>2)&3)<<2)
#pragma unroll
  for (int i = 0; i < 8; ++i) {
    int qq = i * 256 + tid;         // float4 chunks, 2048 total
    int row = qq >> 4, c = qq & 15;
    float4 v = *(const float4*)(hmem + (t0 + (size_t)row) * RR + c * 4);
    int cs = c ^ (((row >> 2) & 3) << 2);
    *(float4*)(sm.ep.Hs + row * 64 + cs * 4) = v;
  }
  __syncthreads();

  const int m0 = (wave >> 1) * 64, n0 = (wave & 1) * 64;
  const int q = lane >> 4, l15 = lane & 15;
  const float g = 1.f / (1.f + __expf(-mem_gate[0]));
  float gbv[4];
#pragma unroll
  for (int i = 0; i < 4; ++i)
    gbv[i] = gen_b2[brow0 + n0 + i * 16 + l15];

  const int d = ob * 2 + (wave & 1);
#pragma unroll
  for (int mf = 0; mf < 4; ++mf)
#pragma unroll
    for (int rg = 0; rg < 4; ++rg) {
      int trow = m0 + mf * 16 + q * 4 + rg;
      int swz  = ((trow >> 2) & 3) << 2;
      float val = 0.f;
#pragma unroll
      for (int nf = 0; nf < 4; ++nf) {
        int r = nf * 16 + l15;
        int idx = trow * 64 + (((r >> 2) ^ swz) << 2) + (r & 3);
        val += (acc[mf][nf][rg] + gbv[nf]) * sm.ep.Hs[idx];
      }
      val += __shfl_xor(val, 1);
      val += __shfl_xor(val, 2);
      val += __shfl_xor(val, 4);
      val += __shfl_xor(val, 8);
      if (l15 == 0) {
        size_t gi = (t0 + trow) * DIMX + d;
        y[gi] = ybase[gi] + g * val;
      }
    }
}

// ---------------------------------------------------------------------------
extern "C" void kernel_launch(void* const* d_in, const int* in_sizes, int n_in,
                              void* d_out, int out_size, void* d_ws, size_t ws_size,
                              hipStream_t stream) {
  const float* x        = (const float*)d_in[0];
  const float* m_tok    = (const float*)d_in[1];
  const float* W1       = (const float*)d_in[2];
  const float* W2       = (const float*)d_in[3];
  const float* W3       = (const float*)d_in[4];
  const float* b1       = (const float*)d_in[5];
  const float* b2       = (const float*)d_in[6];
  const float* b3       = (const float*)d_in[7];
  const float* gen_w1   = (const float*)d_in[8];
  const float* gen_b1   = (const float*)d_in[9];
  const float* gen_w2   = (const float*)d_in[10];
  const float* gen_b2   = (const float*)d_in[11];
  const float* mem_gate = (const float*)d_in[12];
  float* y = (float*)d_out;

  char* ws = (char*)d_ws;
#define KB(v) ((size_t)(v) << 10)
  unsigned short* xb    = (unsigned short*)(ws);               // 1 MB
  unsigned short* hgb   = (unsigned short*)(ws + KB(1024));    // 1 MB
  unsigned short* hb    = (unsigned short*)(ws + KB(2048));    // 4 MB
  float* up    = (float*)(ws + KB(6144));                      // 4 MB
  float* hm    = (float*)(ws + KB(10240));                     // 512 KB
  float* yp    = (float*)(ws + KB(10752));                     // 16 MB (8 slices)
  float* ybase = (float*)(ws + KB(27136));                     // 2 MB
  unsigned short* W1b = (unsigned short*)(ws + KB(29184));     // 2 MB
  unsigned short* W2b = (unsigned short*)(ws + KB(31232));     // 2 MB
  unsigned short* W3b = (unsigned short*)(ws + KB(33280));     // 2 MB
  unsigned short* w2b = (unsigned short*)(ws + KB(35328));     // 96 MB
#undef KB

  prep_kernel<<<256, 256, 0, stream>>>(x, m_tok, gen_w1, gen_b1, W1, W2, W3,
                                       xb, hgb, W1b, W2b, W3b);
  cast_bf16_kernel<<<24576, 256, 0, stream>>>(gen_w2, w2b);

  // base FFN
  ffn12_kernel<<<256, 256, 0, stream>>>(xb, W1b, W2b, b1, b2, hb);
  gemm3p_kernel<<<dim3(32, 8), 256, 0, stream>>>(hb, W3b, yp);
  yreduce_kernel<<<512, 256, 0, stream>>>(yp, b3, ybase);

  // memory path
  memuv_kernel<<<4096, 256, 0, stream>>>(hgb, w2b, gen_b2, xb, up);
  hmem_kernel<<<256, 256, 0, stream>>>(up, hm);
  memy_kernel<<<2048, 256, 0, stream>>>(hgb, w2b, gen_b2, hm, ybase, mem_gate, y);
}

// Round 6
// 527.924 us; speedup vs baseline: 1.0439x; 1.0439x over previous
//
#include <hip/hip_runtime.h>
#include <cstdint>
#include <cstddef>

// Problem dims (fixed)
#define TOK   1024   // B*T
#define DIMX  512
#define HID   2048
#define DM    256
#define GENH  512
#define RR    64
#define O3BASE 65536 // start row of path-3 block in gen_w2 (2*R*DIM)

typedef __bf16 bf16x8 __attribute__((ext_vector_type(8)));
typedef float  f32x4  __attribute__((ext_vector_type(4)));

__device__ __forceinline__ unsigned short f2bf(float f) {
  union { float f; uint32_t u; } v; v.f = f;
  return (unsigned short)((v.u + 0x7fffu + ((v.u >> 16) & 1u)) >> 16);
}
__device__ __forceinline__ float bf2f(unsigned short h) {
  union { uint32_t u; float f; } v; v.u = (uint32_t)h << 16;
  return v.f;
}
__device__ __forceinline__ float silu_f(float x) { return x / (1.f + __expf(-x)); }

__device__ __forceinline__ void async_copy16(const void* g, void* l) {
  __builtin_amdgcn_global_load_lds(
      (const __attribute__((address_space(1))) void*)g,
      (__attribute__((address_space(3))) void*)l, 16, 0, 0);
}

__device__ __forceinline__ void cast8(const float* __restrict__ src,
                                      unsigned short* __restrict__ dst, size_t i) {
  float4 v0 = *(const float4*)(src + i);
  float4 v1 = *(const float4*)(src + i + 4);
  ushort4 h0, h1;
  h0.x = f2bf(v0.x); h0.y = f2bf(v0.y); h0.z = f2bf(v0.z); h0.w = f2bf(v0.w);
  h1.x = f2bf(v1.x); h1.y = f2bf(v1.y); h1.z = f2bf(v1.z); h1.w = f2bf(v1.w);
  *(ushort4*)(dst + i)     = h0;
  *(ushort4*)(dst + i + 4) = h1;
}

// ---------------------------------------------------------------------------
// f32 -> bf16 cast (for gen_w2)
// ---------------------------------------------------------------------------
__global__ __launch_bounds__(256) void cast_bf16_kernel(
    const float* __restrict__ src, unsigned short* __restrict__ dst) {
  cast8(src, dst, ((size_t)blockIdx.x * 256 + threadIdx.x) * 8);
}

// ---------------------------------------------------------------------------
// Stage one [ROWS x 64] bf16 tile into LDS via global_load_lds width=16,
// fetch-side XOR swizzle (chunk' = chunk ^ (row&7)) -> conflict-free b128.
// ---------------------------------------------------------------------------
template<int ROWS>
__device__ __forceinline__ void stage_tile(
    const unsigned short* __restrict__ base, size_t row0, int stride, int kofs,
    unsigned short* Ls, int tid) {
  constexpr int IT = ROWS / 32;           // 16B chunks per thread
  const int wave = tid >> 6, lane = tid & 63;
#pragma unroll
  for (int j = 0; j < IT; ++j) {
    int s   = wave * (IT * 64) + j * 64 + lane;   // linear 16B slot
    int row = s >> 3;
    int kc  = (s & 7) ^ (row & 7);                // fetch-side swizzle
    const unsigned short* g = base + (row0 + (size_t)row) * (size_t)stride + kofs + kc * 8;
    async_copy16(g, (char*)Ls + wave * (IT * 1024) + j * 1024);
  }
}

// ---------------------------------------------------------------------------
// Core: C[MF*32 x 128] = A[MF*32 x K] @ B[128 x K]^T (bf16, K-contig) via
// mfma_f32_16x16x32_bf16, 4 waves 2x2. Ends with __syncthreads().
// ---------------------------------------------------------------------------
template<int KLEN, int MF>
__device__ __forceinline__ void mfma_tile_nt(
    const unsigned short* __restrict__ Abf, size_t a_row0, int astride,
    const unsigned short* __restrict__ Bbf, size_t b_row0, int bstride, int k0,
    unsigned short* As, unsigned short* Bs, f32x4 (&acc)[MF][4]) {
  const int tid  = threadIdx.x;
  const int lane = tid & 63;
  const int wave = tid >> 6;
  const int m0 = (wave >> 1) * (MF * 16), n0 = (wave & 1) * 64;

  for (int kk = 0; kk < KLEN; kk += 64) {
    stage_tile<MF * 32>(Abf, a_row0, astride, k0 + kk, As, tid);
    stage_tile<128>(Bbf, b_row0, bstride, k0 + kk, Bs, tid);
    __syncthreads();
#pragma unroll
    for (int ks = 0; ks < 2; ++ks) {
      int cbase = ks * 4 + (lane >> 4);
      int koff  = (cbase ^ (lane & 7)) * 8;   // row&7 == lane&7 for all frags
      bf16x8 a[MF], b[4];
#pragma unroll
      for (int mf = 0; mf < MF; ++mf)
        a[mf] = *(const bf16x8*)(As + (m0 + mf * 16 + (lane & 15)) * 64 + koff);
#pragma unroll
      for (int nf = 0; nf < 4; ++nf)
        b[nf] = *(const bf16x8*)(Bs + (n0 + nf * 16 + (lane & 15)) * 64 + koff);
#pragma unroll
      for (int mf = 0; mf < MF; ++mf)
#pragma unroll
        for (int nf = 0; nf < 4; ++nf)
          acc[mf][nf] = __builtin_amdgcn_mfma_f32_16x16x32_bf16(
              a[mf], b[nf], acc[mf][nf], 0, 0, 0);
    }
    __syncthreads();
  }
}

template<int MF>
__device__ __forceinline__ void zero_accN(f32x4 (&acc)[MF][4]) {
#pragma unroll
  for (int i = 0; i < MF; ++i)
#pragma unroll
    for (int j = 0; j < 4; ++j) {
      f32x4 z = {0.f, 0.f, 0.f, 0.f};
      acc[i][j] = z;
    }
}

// ---------------------------------------------------------------------------
// prep: hg = silu(m_tok @ gen_w1^T + gen_b1) -> bf16; x -> bf16;
// also casts W1/W2/W3 to bf16 (folded to save launches).
// ---------------------------------------------------------------------------
__global__ __launch_bounds__(256) void prep_kernel(
    const float* __restrict__ x, const float* __restrict__ m_tok,
    const float* __restrict__ gen_w1, const float* __restrict__ gen_b1,
    const float* __restrict__ W1, const float* __restrict__ W2,
    const float* __restrict__ W3,
    unsigned short* __restrict__ xb, unsigned short* __restrict__ hgb,
    unsigned short* __restrict__ W1b, unsigned short* __restrict__ W2b,
    unsigned short* __restrict__ W3b) {
  __shared__ float mt[4 * DM];
  const int tid = threadIdx.x;
  const size_t t0 = (size_t)blockIdx.x * 4;
#pragma unroll
  for (int k = 0; k < 4; ++k) mt[k * 256 + tid] = m_tok[t0 * DM + k * 256 + tid];
#pragma unroll
  for (int k = 0; k < 8; ++k) {
    size_t idx = t0 * DIMX + k * 256 + tid;
    xb[idx] = f2bf(x[idx]);
  }
  // folded weight casts: 1,048,576 elems each = 2 chunks/thread each
  {
    size_t base = ((size_t)blockIdx.x * 256 + tid) * 8;
#pragma unroll
    for (int it = 0; it < 2; ++it) {
      size_t idx = base + (size_t)it * 524288;
      cast8(W1, W1b, idx);
      cast8(W2, W2b, idx);
      cast8(W3, W3b, idx);
    }
  }
  __syncthreads();
#pragma unroll
  for (int hh = 0; hh < 2; ++hh) {
    int h = hh * 256 + tid;
    float a0, a1, a2, a3;
    a0 = a1 = a2 = a3 = gen_b1[h];
    const float* wr = gen_w1 + (size_t)h * DM;
    for (int d = 0; d < DM; d += 4) {
      float4 w = *(const float4*)(wr + d);
      a0 += w.x * mt[d]       + w.y * mt[d + 1]       + w.z * mt[d + 2]       + w.w * mt[d + 3];
      a1 += w.x * mt[256 + d] + w.y * mt[256 + d + 1] + w.z * mt[256 + d + 2] + w.w * mt[256 + d + 3];
      a2 += w.x * mt[512 + d] + w.y * mt[512 + d + 1] + w.z * mt[512 + d + 2] + w.w * mt[512 + d + 3];
      a3 += w.x * mt[768 + d] + w.y * mt[768 + d + 1] + w.z * mt[768 + d + 2] + w.w * mt[768 + d + 3];
    }
    hgb[(t0 + 0) * GENH + h] = f2bf(silu_f(a0));
    hgb[(t0 + 1) * GENH + h] = f2bf(silu_f(a1));
    hgb[(t0 + 2) * GENH + h] = f2bf(silu_f(a2));
    hgb[(t0 + 3) * GENH + h] = f2bf(silu_f(a3));
  }
}

// ---------------------------------------------------------------------------
// ffn12: fused x@W1^T / x@W2^T + bias + silu-mul -> hb (bf16).
// Tile 32 tok x 128 o, grid 512 blocks (2/CU). Waves 2x2 (16x64 each).
// ---------------------------------------------------------------------------
__global__ __launch_bounds__(256) void ffn12_kernel(
    const unsigned short* __restrict__ xb, const unsigned short* __restrict__ W1b,
    const unsigned short* __restrict__ W2b, const float* __restrict__ pb1,
    const float* __restrict__ pb2, unsigned short* __restrict__ hb) {
  __shared__ unsigned short As[32 * 64];
  __shared__ unsigned short B1s[128 * 64];
  __shared__ unsigned short B2s[128 * 64];
  const int tid = threadIdx.x, lane = tid & 63, wave = tid >> 6;
  const int ob = blockIdx.x & 15, tb = blockIdx.x >> 4;
  const size_t t0 = (size_t)tb * 32, o0 = (size_t)ob * 128;
  const int m0 = (wave >> 1) * 16, n0 = (wave & 1) * 64;

  f32x4 acc1[4], acc2[4];
#pragma unroll
  for (int j = 0; j < 4; ++j) {
    f32x4 z = {0.f, 0.f, 0.f, 0.f};
    acc1[j] = z; acc2[j] = z;
  }

  for (int kk = 0; kk < DIMX; kk += 64) {
    stage_tile<32>(xb, t0, DIMX, kk, As, tid);
    stage_tile<128>(W1b, o0, DIMX, kk, B1s, tid);
    stage_tile<128>(W2b, o0, DIMX, kk, B2s, tid);
    __syncthreads();
#pragma unroll
    for (int ks = 0; ks < 2; ++ks) {
      int cbase = ks * 4 + (lane >> 4);
      int koff  = (cbase ^ (lane & 7)) * 8;
      bf16x8 a, b1[4], b2[4];
      a = *(const bf16x8*)(As + (m0 + (lane & 15)) * 64 + koff);
#pragma unroll
      for (int nf = 0; nf < 4; ++nf) {
        b1[nf] = *(const bf16x8*)(B1s + (n0 + nf * 16 + (lane & 15)) * 64 + koff);
        b2[nf] = *(const bf16x8*)(B2s + (n0 + nf * 16 + (lane & 15)) * 64 + koff);
      }
#pragma unroll
      for (int nf = 0; nf < 4; ++nf) {
        acc1[nf] = __builtin_amdgcn_mfma_f32_16x16x32_bf16(a, b1[nf], acc1[nf], 0, 0, 0);
        acc2[nf] = __builtin_amdgcn_mfma_f32_16x16x32_bf16(a, b2[nf], acc2[nf], 0, 0, 0);
      }
    }
    __syncthreads();
  }

  const int q = lane >> 4;
  float b1v[4], b2v[4];
#pragma unroll
  for (int nf = 0; nf < 4; ++nf) {
    b1v[nf] = pb1[o0 + n0 + nf * 16 + (lane & 15)];
    b2v[nf] = pb2[o0 + n0 + nf * 16 + (lane & 15)];
  }
#pragma unroll
  for (int nf = 0; nf < 4; ++nf)
#pragma unroll
    for (int rg = 0; rg < 4; ++rg) {
      size_t trow = t0 + m0 + q * 4 + rg;
      size_t col  = o0 + n0 + nf * 16 + (lane & 15);
      float v1 = acc1[nf][rg] + b1v[nf];
      float v2 = acc2[nf][rg] + b2v[nf];
      hb[trow * HID + col] = f2bf(silu_f(v1) * v2);
    }
}

// ---------------------------------------------------------------------------
// gemm3p: yp[slice] = hb @ W3b^T (partial K), 64x128 tiles, plain stores.
// grid (64, 4): 16 t-tiles x 4 o-tiles x 4 K-slices (KTILE=512) -> 256 blocks.
// ---------------------------------------------------------------------------
__global__ __launch_bounds__(256) void gemm3p_kernel(
    const unsigned short* __restrict__ hb, const unsigned short* __restrict__ W3b,
    float* __restrict__ yp) {
  __shared__ unsigned short As[64 * 64];
  __shared__ unsigned short Bs[128 * 64];
  const int ob = blockIdx.x & 3, tb = blockIdx.x >> 2;
  const size_t o0 = (size_t)ob * 128, t0 = (size_t)tb * 64;
  const int k0 = blockIdx.y * 512;
  f32x4 acc[2][4];
  zero_accN<2>(acc);
  mfma_tile_nt<512, 2>(hb, t0, HID, W3b, o0, HID, k0, As, Bs, acc);

  const int tid = threadIdx.x, lane = tid & 63, wave = tid >> 6;
  const int m0 = (wave >> 1) * 32, n0 = (wave & 1) * 64;
  float* out = yp + (size_t)blockIdx.y * (TOK * DIMX);
#pragma unroll
  for (int nf = 0; nf < 4; ++nf) {
    int n = n0 + nf * 16 + (lane & 15);
#pragma unroll
    for (int mf = 0; mf < 2; ++mf) {
      int mb = m0 + mf * 16 + ((lane >> 4) << 2);
#pragma unroll
      for (int rg = 0; rg < 4; ++rg)
        out[(t0 + mb + rg) * DIMX + o0 + n] = acc[mf][nf][rg];
    }
  }
}

// ---------------------------------------------------------------------------
// yreduce: ybase = b3 + sum of 4 yp slices. float4/thread.
// ---------------------------------------------------------------------------
__global__ __launch_bounds__(256) void yreduce_kernel(
    const float* __restrict__ yp, const float* __restrict__ b3,
    float* __restrict__ ybase) {
  size_t i = ((size_t)blockIdx.x * 256 + threadIdx.x) * 4;
  int d = (int)(i & (DIMX - 1));
  float4 s = *(const float4*)(b3 + d);
#pragma unroll
  for (int p = 0; p < 4; ++p) {
    float4 v = *(const float4*)(yp + (size_t)p * (TOK * DIMX) + i);
    s.x += v.x; s.y += v.y; s.z += v.z; s.w += v.w;
  }
  *(float4*)(ybase + i) = s;
}

// ---------------------------------------------------------------------------
// memuv: fused paths 1&2. Block = [128 tok x 128 o] tile of w; epilogue
// contracts vs x staged in LDS [128x128] bf16 with address swizzle; leaders
// store float4 partials to up[p][j][t].
// Grid map: bx = (strip%8) + 8*(tb + 8*(strip>>3)) -> XCD(bx)=strip%8 AND the
// 8 tb-sharers of a strip are 8 consecutive blocks on that XCD: strip fetched
// from HBM once, ~20 resident strips x 128 KB = 2.5 MB < 4 MB L2.
// LDS exactly 32 KB -> 5 blocks/CU.
// ---------------------------------------------------------------------------
union SmemUV {
  struct { unsigned short As[8192], Bs[8192]; } ab;
  struct { unsigned short Xs[128 * 128]; } ep;
};

__global__ __launch_bounds__(256) void memuv_kernel(
    const unsigned short* __restrict__ hgb, const unsigned short* __restrict__ w2b,
    const float* __restrict__ gen_b2, const unsigned short* __restrict__ xb,
    float* __restrict__ up) {
  __shared__ SmemUV sm;
  const int bx = blockIdx.x;
  const int s8 = bx & 7, w = bx >> 3;
  const int tb = w & 7, strip = (w >> 3) * 8 + s8;   // 0..511
  const size_t o0 = (size_t)strip * 128, t0 = (size_t)tb * 128;
  const int j  = strip >> 2;        // u column (0..127)
  const int d0 = (strip & 3) * 128; // d-range within the r row

  f32x4 acc[4][4];
  zero_accN<4>(acc);
  mfma_tile_nt<GENH, 4>(hgb, t0, GENH, w2b, o0, GENH, 0, sm.ab.As, sm.ab.Bs, acc);

  const int tid = threadIdx.x, lane = tid & 63, wave = tid >> 6;
  // stage x tile [128 t x 128 d] bf16 with chunk swizzle ^(((row>>2)&3)<<1)
#pragma unroll
  for (int i = 0; i < 8; ++i) {
    int qq = i * 256 + tid;         // 8-short chunks, 2048 total
    int row = qq >> 4, c = qq & 15;
    const unsigned short* src = xb + (t0 + (size_t)row) * DIMX + d0 + c * 8;
    ushort4 v0 = *(const ushort4*)src;
    ushort4 v1 = *(const ushort4*)(src + 4);
    int cs = c ^ (((row >> 2) & 3) << 1);
    unsigned short* dst = sm.ep.Xs + row * 128 + cs * 8;
    *(ushort4*)dst = v0;
    *(ushort4*)(dst + 4) = v1;
  }
  __syncthreads();

  const int m0 = (wave >> 1) * 64, n0 = (wave & 1) * 64;
  const int q = lane >> 4, l15 = lane & 15;
  float gbv[4];
#pragma unroll
  for (int i = 0; i < 4; ++i)
    gbv[i] = gen_b2[o0 + n0 + i * 16 + l15];

  const int p = (strip & 3) * 2 + (wave & 1);
  float* upd = up + (size_t)p * (128 * 1024) + (size_t)j * 1024 + t0;
#pragma unroll
  for (int mf = 0; mf < 4; ++mf) {
    f32x4 vals;
#pragma unroll
    for (int rg = 0; rg < 4; ++rg) {
      int trow = m0 + mf * 16 + q * 4 + rg;
      int swz  = ((trow >> 2) & 3) << 1;
      float val = 0.f;
#pragma unroll
      for (int nf = 0; nf < 4; ++nf) {
        int col = n0 + nf * 16 + l15;
        int idx = trow * 128 + (((col >> 3) ^ swz) << 3) + (col & 7);
        val += (acc[mf][nf][rg] + gbv[nf]) * bf2f(sm.ep.Xs[idx]);
      }
      val += __shfl_xor(val, 1);
      val += __shfl_xor(val, 2);
      val += __shfl_xor(val, 4);
      val += __shfl_xor(val, 8);
      vals[rg] = val;
    }
    if (l15 == 0)
      *(f32x4*)(upd + m0 + mf * 16 + q * 4) = vals;
  }
}

// ---------------------------------------------------------------------------
// hmem: u = sum of 8 partials (coalesced in t); h_mem = silu(u1)*u2, [t][r].
// ---------------------------------------------------------------------------
__global__ __launch_bounds__(256) void hmem_kernel(
    const float* __restrict__ up, float* __restrict__ hm) {
  int i = blockIdx.x * 256 + threadIdx.x;  // 65536
  int t = i & 1023, r = i >> 10;           // r in 0..63
  float u1 = 0.f, u2 = 0.f;
#pragma unroll
  for (int p = 0; p < 8; ++p) {
    u1 += up[(size_t)p * (128 * 1024) + (size_t)r * 1024 + t];
    u2 += up[(size_t)p * (128 * 1024) + (size_t)(64 + r) * 1024 + t];
  }
  hm[(size_t)t * RR + r] = silu_f(u1) * u2;
}

// ---------------------------------------------------------------------------
// memy: fused path 3. Epilogue contracts vs h_mem in LDS [128x64] f32 with
// chunk swizzle; single-writer y = ybase + g*val. Strip-consecutive XCD map.
// LDS exactly 32 KB.
// ---------------------------------------------------------------------------
union SmemY {
  struct { unsigned short As[8192], Bs[8192]; } ab;
  struct { float Hs[128 * 64]; } ep;
};

__global__ __launch_bounds__(256) void memy_kernel(
    const unsigned short* __restrict__ hgb, const unsigned short* __restrict__ w2b,
    const float* __restrict__ gen_b2, const float* __restrict__ hmem,
    const float* __restrict__ ybase, const float* __restrict__ mem_gate,
    float* __restrict__ y) {
  __shared__ SmemY sm;
  const int bx = blockIdx.x;
  const int s8 = bx & 7, w = bx >> 3;
  const int tb = w & 7, strip = (w >> 3) * 8 + s8;   // 0..255
  const size_t brow0 = (size_t)O3BASE + (size_t)strip * 128;
  const size_t t0 = (size_t)tb * 128;

  f32x4 acc[4][4];
  zero_accN<4>(acc);
  mfma_tile_nt<GENH, 4>(hgb, t0, GENH, w2b, brow0, GENH, 0, sm.ab.As, sm.ab.Bs, acc);

  const int tid = threadIdx.x, lane = tid & 63, wave = tid >> 6;
  // stage h_mem tile [128 t x 64 r] f32, chunk swizzle ^(((row>>2)&3)<<2)
#pragma unroll
  for (int i = 0; i < 8; ++i) {
    int qq = i * 256 + tid;         // float4 chunks, 2048 total
    int row = qq >> 4, c = qq & 15;
    float4 v = *(const float4*)(hmem + (t0 + (size_t)row) * RR + c * 4);
    int cs = c ^ (((row >> 2) & 3) << 2);
    *(float4*)(sm.ep.Hs + row * 64 + cs * 4) = v;
  }
  __syncthreads();

  const int m0 = (wave >> 1) * 64, n0 = (wave & 1) * 64;
  const int q = lane >> 4, l15 = lane & 15;
  const float g = 1.f / (1.f + __expf(-mem_gate[0]));
  float gbv[4];
#pragma unroll
  for (int i = 0; i < 4; ++i)
    gbv[i] = gen_b2[brow0 + n0 + i * 16 + l15];

  const int d = strip * 2 + (wave & 1);
#pragma unroll
  for (int mf = 0; mf < 4; ++mf)
#pragma unroll
    for (int rg = 0; rg < 4; ++rg) {
      int trow = m0 + mf * 16 + q * 4 + rg;
      int swz  = ((trow >> 2) & 3) << 2;
      float val = 0.f;
#pragma unroll
      for (int nf = 0; nf < 4; ++nf) {
        int r = nf * 16 + l15;
        int idx = trow * 64 + (((r >> 2) ^ swz) << 2) + (r & 3);
        val += (acc[mf][nf][rg] + gbv[nf]) * sm.ep.Hs[idx];
      }
      val += __shfl_xor(val, 1);
      val += __shfl_xor(val, 2);
      val += __shfl_xor(val, 4);
      val += __shfl_xor(val, 8);
      if (l15 == 0) {
        size_t gi = (t0 + trow) * DIMX + d;
        y[gi] = ybase[gi] + g * val;
      }
    }
}

// ---------------------------------------------------------------------------
extern "C" void kernel_launch(void* const* d_in, const int* in_sizes, int n_in,
                              void* d_out, int out_size, void* d_ws, size_t ws_size,
                              hipStream_t stream) {
  const float* x        = (const float*)d_in[0];
  const float* m_tok    = (const float*)d_in[1];
  const float* W1       = (const float*)d_in[2];
  const float* W2       = (const float*)d_in[3];
  const float* W3       = (const float*)d_in[4];
  const float* b1       = (const float*)d_in[5];
  const float* b2       = (const float*)d_in[6];
  const float* b3       = (const float*)d_in[7];
  const float* gen_w1   = (const float*)d_in[8];
  const float* gen_b1   = (const float*)d_in[9];
  const float* gen_w2   = (const float*)d_in[10];
  const float* gen_b2   = (const float*)d_in[11];
  const float* mem_gate = (const float*)d_in[12];
  float* y = (float*)d_out;

  char* ws = (char*)d_ws;
#define KB(v) ((size_t)(v) << 10)
  unsigned short* xb    = (unsigned short*)(ws);               // 1 MB
  unsigned short* hgb   = (unsigned short*)(ws + KB(1024));    // 1 MB
  unsigned short* hb    = (unsigned short*)(ws + KB(2048));    // 4 MB
  float* up    = (float*)(ws + KB(6144));                      // 4 MB
  float* hm    = (float*)(ws + KB(10240));                     // 512 KB
  float* yp    = (float*)(ws + KB(10752));                     // 8 MB (4 slices)
  float* ybase = (float*)(ws + KB(19200));                     // 2 MB
  unsigned short* W1b = (unsigned short*)(ws + KB(21248));     // 2 MB
  unsigned short* W2b = (unsigned short*)(ws + KB(23296));     // 2 MB
  unsigned short* W3b = (unsigned short*)(ws + KB(25344));     // 2 MB
  unsigned short* w2b = (unsigned short*)(ws + KB(27392));     // 96 MB
#undef KB

  prep_kernel<<<256, 256, 0, stream>>>(x, m_tok, gen_w1, gen_b1, W1, W2, W3,
                                       xb, hgb, W1b, W2b, W3b);
  cast_bf16_kernel<<<24576, 256, 0, stream>>>(gen_w2, w2b);

  // base FFN
  ffn12_kernel<<<512, 256, 0, stream>>>(xb, W1b, W2b, b1, b2, hb);
  gemm3p_kernel<<<dim3(64, 4), 256, 0, stream>>>(hb, W3b, yp);
  yreduce_kernel<<<512, 256, 0, stream>>>(yp, b3, ybase);

  // memory path
  memuv_kernel<<<4096, 256, 0, stream>>>(hgb, w2b, gen_b2, xb, up);
  hmem_kernel<<<256, 256, 0, stream>>>(up, hm);
  memy_kernel<<<2048, 256, 0, stream>>>(hgb, w2b, gen_b2, hm, ybase, mem_gate, y);
}